// Round 2
// baseline (536.590 us; speedup 1.0000x reference)
//
#include <hip/hip_runtime.h>
#include <hip/hip_bf16.h>

// Submanifold sparse 3D conv — output-stationary bf16-MFMA version.
//
// Identity used: offset lists are symmetric (offs[25-m] = -offs[m]), so
//   out[imap[m,p]] += feats[omap[m,p]] @ kernel[26 - kk(m)]
// is exact, and imap[m] is SORTED ASCENDING -> block-range partitioning of
// outputs with no global atomics. Accumulate in LDS (fp32, ds_add_f32),
// write out once. Center fused as identity-map item with kernel[13].
//
// Pre-passes (into d_ws):
//   Wt[27][o][c] bf16  (transposed weights, fragment-ready, 221184 B)
//   ranges[26][nb+1]   (lower_bound(imap[m], 256*b) per block)

#define CIN 64
#define COUT 64
#define BROWS 256
#define NOFF 26

typedef short bf16x8 __attribute__((ext_vector_type(8)));
typedef float f32x4 __attribute__((ext_vector_type(4)));

__device__ inline unsigned short bfbits(float f) {
    unsigned u = __builtin_bit_cast(unsigned, f);
    u += 0x7fffu + ((u >> 16) & 1u);          // round-to-nearest-even
    return (unsigned short)(u >> 16);
}

// ---------------- pre-pass 1: W [27][c][o] f32  ->  Wt [27][o][c] bf16 ----
__global__ __launch_bounds__(256) void prep_wt(const float* __restrict__ W,
                                               unsigned short* __restrict__ Wt) {
    const int k = blockIdx.x;
    for (int idx = threadIdx.x; idx < CIN * COUT; idx += 256) {
        const int c = idx >> 6, o = idx & 63;
        Wt[(k * 64 + o) * 64 + c] = bfbits(W[(k * 64 + c) * 64 + o]);
    }
}

// ---------------- pre-pass 2: per-(offset, block) pair ranges -------------
__global__ __launch_bounds__(256) void prep_ranges(const int* __restrict__ imap,
                                                   int P, int nb1,
                                                   int* __restrict__ ranges) {
    const int idx = blockIdx.x * 256 + threadIdx.x;
    if (idx >= NOFF * nb1) return;
    const int m = idx / nb1, b = idx % nb1;
    const int* a = imap + (size_t)m * P;
    const int target = b * BROWS;
    int lo = 0, hi = P;
    while (lo < hi) {
        const int mid = (lo + hi) >> 1;
        const int v = a[mid];
        const int key = (v < 0) ? 0x7fffffff : v;   // -1 tail pad -> +inf
        if (key < target) lo = mid + 1; else hi = mid;
    }
    ranges[idx] = lo;
}

// ---------------- main kernel ---------------------------------------------
__device__ inline void process_range(
    const float* __restrict__ feats,
    const bf16x8* __restrict__ WtK,      // Wt[kk] rows: [o][c/8]
    const int* __restrict__ imr,         // imap row (nullptr => center/identity)
    const int* __restrict__ omr,
    int p0, int p1, int j0, int lane, float* __restrict__ acc)
{
    const int col = lane & 15, grp = lane >> 4;

    bf16x8 wf[2][4];                     // [ktile][otile] B fragments
#pragma unroll
    for (int kt = 0; kt < 2; ++kt)
#pragma unroll
        for (int ot = 0; ot < 4; ++ot)
            wf[kt][ot] = WtK[(ot * 16 + col) * 8 + kt * 4 + grp];

    for (int pb = p0; pb < p1; pb += 16) {
        const int pr = pb + col;         // pair slot this lane represents
        int im = -1, jl = -1;
        if (pr < p1) {
            if (imr) { im = omr[pr]; jl = imr[pr] - j0; }
            else     { im = pr;      jl = pr - j0; }
        }

        bf16x8 a0 = {0,0,0,0,0,0,0,0}, a1 = {0,0,0,0,0,0,0,0};
        if (im >= 0) {
            const float4* fp = (const float4*)(feats + (size_t)im * 64 + grp * 8);
            const float4 x0 = fp[0], x1 = fp[1];
            const float4* fq = (const float4*)(feats + (size_t)im * 64 + 32 + grp * 8);
            const float4 y0 = fq[0], y1 = fq[1];
            a0[0] = (short)bfbits(x0.x); a0[1] = (short)bfbits(x0.y);
            a0[2] = (short)bfbits(x0.z); a0[3] = (short)bfbits(x0.w);
            a0[4] = (short)bfbits(x1.x); a0[5] = (short)bfbits(x1.y);
            a0[6] = (short)bfbits(x1.z); a0[7] = (short)bfbits(x1.w);
            a1[0] = (short)bfbits(y0.x); a1[1] = (short)bfbits(y0.y);
            a1[2] = (short)bfbits(y0.z); a1[3] = (short)bfbits(y0.w);
            a1[4] = (short)bfbits(y1.x); a1[5] = (short)bfbits(y1.y);
            a1[6] = (short)bfbits(y1.z); a1[7] = (short)bfbits(y1.w);
        }

        f32x4 c0 = {0.f,0.f,0.f,0.f}, c1 = c0, c2 = c0, c3 = c0;
        c0 = __builtin_amdgcn_mfma_f32_16x16x32_bf16(a0, wf[0][0], c0, 0, 0, 0);
        c0 = __builtin_amdgcn_mfma_f32_16x16x32_bf16(a1, wf[1][0], c0, 0, 0, 0);
        c1 = __builtin_amdgcn_mfma_f32_16x16x32_bf16(a0, wf[0][1], c1, 0, 0, 0);
        c1 = __builtin_amdgcn_mfma_f32_16x16x32_bf16(a1, wf[1][1], c1, 0, 0, 0);
        c2 = __builtin_amdgcn_mfma_f32_16x16x32_bf16(a0, wf[0][2], c2, 0, 0, 0);
        c2 = __builtin_amdgcn_mfma_f32_16x16x32_bf16(a1, wf[1][2], c2, 0, 0, 0);
        c3 = __builtin_amdgcn_mfma_f32_16x16x32_bf16(a0, wf[0][3], c3, 0, 0, 0);
        c3 = __builtin_amdgcn_mfma_f32_16x16x32_bf16(a1, wf[1][3], c3, 0, 0, 0);

        // C layout: col=lane&15 (cout within otile), row=(lane>>4)*4+reg (slot)
        const int js0 = __shfl(jl, grp * 4 + 0);
        const int js1 = __shfl(jl, grp * 4 + 1);
        const int js2 = __shfl(jl, grp * 4 + 2);
        const int js3 = __shfl(jl, grp * 4 + 3);
#pragma unroll
        for (int ot = 0; ot < 4; ++ot) {
            const f32x4 cv = (ot == 0) ? c0 : (ot == 1) ? c1 : (ot == 2) ? c2 : c3;
            const int o = ot * 16 + col;
            if (js0 >= 0) atomicAdd(&acc[js0 * 64 + (o ^ ((js0 & 3) << 3))], cv[0]);
            if (js1 >= 0) atomicAdd(&acc[js1 * 64 + (o ^ ((js1 & 3) << 3))], cv[1]);
            if (js2 >= 0) atomicAdd(&acc[js2 * 64 + (o ^ ((js2 & 3) << 3))], cv[2]);
            if (js3 >= 0) atomicAdd(&acc[js3 * 64 + (o ^ ((js3 & 3) << 3))], cv[3]);
        }
    }
}

__global__ __launch_bounds__(512, 4) void spconv_main(
    const float* __restrict__ feats,
    const unsigned short* __restrict__ Wt,   // [27][64][64] bf16 (o-major)
    const int* __restrict__ imap, const int* __restrict__ omap,
    const int* __restrict__ ranges,
    float* __restrict__ out, int N, int P, int nb1)
{
    __shared__ float acc[BROWS * 64];        // 64 KiB, XOR-swizzled columns
    const int tid = threadIdx.x, w = tid >> 6, lane = tid & 63;
    const int j0 = blockIdx.x * BROWS;

    for (int idx = tid; idx < BROWS * 64; idx += 512) acc[idx] = 0.f;
    __syncthreads();

    // 26 offsets round-robin across 8 waves (reversed-map reading)
    for (int m = w; m < NOFF; m += 8) {
        const int p0 = ranges[m * nb1 + blockIdx.x];
        const int p1 = ranges[m * nb1 + blockIdx.x + 1];
        if (p0 >= p1) continue;
        const int kkw = 26 - (m < 13 ? m : m + 1);   // reversed kernel index
        process_range(feats, (const bf16x8*)(Wt + kkw * 4096),
                      imap + (size_t)m * P, omap + (size_t)m * P,
                      p0, p1, j0, lane, acc);
    }
    // center: identity map, kernel 13, split 32 rows per wave
    {
        const int p0 = j0 + w * 32;
        const int p1 = min(j0 + (w + 1) * 32, N);
        if (p0 < p1)
            process_range(feats, (const bf16x8*)(Wt + 13 * 4096),
                          nullptr, nullptr, p0, p1, j0, lane, acc);
    }
    __syncthreads();

    const int rows = min(BROWS, N - j0);
    for (int idx = tid; idx < rows * 64; idx += 512) {
        const int r = idx >> 6, o = idx & 63;
        out[(size_t)(j0 + r) * 64 + o] = acc[r * 64 + (o ^ ((r & 3) << 3))];
    }
}

// ---------------- fallback (round-0, fp32 + atomics) ----------------------
template <int MODE>
__global__ __launch_bounds__(256) void spconv_fb(
    const float* __restrict__ feats, const float* __restrict__ W,
    const int* __restrict__ imap, const int* __restrict__ omap,
    float* __restrict__ out, int npairs)
{
    __shared__ float4 wt4[16 * 64];
    const int tid = threadIdx.x, koff = blockIdx.y;
    const float* Wk;
    const int* im = nullptr; const int* om = nullptr;
    if (MODE == 0) Wk = W + 13 * (CIN * COUT);
    else {
        const int kk = (koff < 13) ? koff : koff + 1;
        Wk = W + (size_t)kk * (CIN * COUT);
        im = imap + (size_t)koff * npairs; om = omap + (size_t)koff * npairs;
    }
    float* wts = (float*)wt4;
    for (int idx = tid; idx < CIN * COUT; idx += 256) {
        const int c = idx >> 6, o = idx & 63;
        wts[((c >> 2) * 64 + o) * 4 + (c & 3)] = Wk[idx];
    }
    __syncthreads();
    const int o = tid & 63, w = tid >> 6;
    const int base = blockIdx.x * 256 + w * 64;
    const float4* f4p = (const float4*)feats;
    for (int n = 0; n < 64; ++n) {
        const int p = base + n;
        if (p >= npairs) break;
        int i, j;
        if (MODE == 0) { i = p; j = p; }
        else { i = im[p]; if (i < 0) continue; j = om[p]; }
        i = __builtin_amdgcn_readfirstlane(i);
        float a = 0.f;
#pragma unroll
        for (int c4 = 0; c4 < 16; ++c4) {
            const float4 f = f4p[(size_t)i * 16 + c4];
            const float4 wv = wt4[c4 * 64 + o];
            a += f.x * wv.x + f.y * wv.y + f.z * wv.z + f.w * wv.w;
        }
        if (MODE == 0) out[(size_t)j * COUT + o] = a;
        else atomicAdd(&out[(size_t)j * COUT + o], a);
    }
}

extern "C" void kernel_launch(void* const* d_in, const int* in_sizes, int n_in,
                              void* d_out, int out_size, void* d_ws, size_t ws_size,
                              hipStream_t stream) {
    const float* feats = (const float*)d_in[0];
    const float* W     = (const float*)d_in[1];
    const int* imap    = (const int*)d_in[2];
    const int* omap    = (const int*)d_in[3];
    float* out         = (float*)d_out;

    const int N = in_sizes[0] / CIN;
    const int P = in_sizes[2] / NOFF;
    const int nb = (N + BROWS - 1) / BROWS;
    const int nb1 = nb + 1;

    const size_t wt_bytes = 27 * 64 * 64 * sizeof(unsigned short);  // 221184
    const size_t rg_bytes = (size_t)NOFF * nb1 * sizeof(int);
    if (ws_size < wt_bytes + rg_bytes) {
        // scratch too small: correct fp32 fallback
        dim3 blk(256);
        dim3 gc((N + 255) / 256, 1);
        spconv_fb<0><<<gc, blk, 0, stream>>>(feats, W, nullptr, nullptr, out, N);
        dim3 go((P + 255) / 256, NOFF);
        spconv_fb<1><<<go, blk, 0, stream>>>(feats, W, imap, omap, out, P);
        return;
    }

    unsigned short* Wt = (unsigned short*)d_ws;
    int* ranges = (int*)((char*)d_ws + wt_bytes);

    prep_wt<<<27, 256, 0, stream>>>(W, Wt);
    prep_ranges<<<(NOFF * nb1 + 255) / 256, 256, 0, stream>>>(imap, P, nb1, ranges);
    spconv_main<<<nb, 512, 0, stream>>>(feats, Wt, imap, omap, ranges, out, N, P, nb1);
}

// Round 3
// 163.341 us; speedup vs baseline: 3.2851x; 3.2851x over previous
//
#include <hip/hip_runtime.h>

// Submanifold sparse 3D conv — v3: offset-synchronous, output-stationary in
// REGISTERS. Each wave owns 16 output rows; loops over 27 items (26 offsets,
// reversed-map + center). Per item: ranges table gives <=16 pairs, a per-wave
// LDS permute maps them to columns, lanes gather real input rows, 8 MFMA
// accumulate into persistent f32x4 c[4]. No atomics anywhere. W double-
// buffered in LDS (bf16, XOR-swizzled 16B units).
//
// Map identity (verified R1, absmax 7.8e-3): offset lists are symmetric, so
//   out[imap[m,p]] += feats[omap[m,p]] @ kernel[26 - kk(m)]
// with imap[m] sorted ascending -> range partitioning of outputs.

#define CIN 64
#define COUT 64
#define TROWS 16          // output rows per wave
#define NOFF 26

typedef short bf16x8 __attribute__((ext_vector_type(8)));
typedef unsigned short ushort8 __attribute__((ext_vector_type(8)));
typedef float f32x4 __attribute__((ext_vector_type(4)));

__device__ __host__ inline unsigned short bfbits(float f) {
    unsigned u = __builtin_bit_cast(unsigned, f);
    u += 0x7fffu + ((u >> 16) & 1u);          // RNE
    return (unsigned short)(u >> 16);
}

// item -> kernel index (26-kk reversal for offsets; 13 for center item 26)
__device__ inline int kk_of_item(int i) {
    return (i == 26) ? 13 : 26 - (i < 13 ? i : i + 1);
}

// ---------- pre-pass 1: W [27][c][o] f32 -> Wt [27][o][c] bf16 ------------
__global__ __launch_bounds__(256) void prep_wt(const float* __restrict__ W,
                                               unsigned short* __restrict__ Wt) {
    const int k = blockIdx.x;
    for (int idx = threadIdx.x; idx < CIN * COUT; idx += 256) {
        const int c = idx >> 6, o = idx & 63;
        Wt[(k * 64 + o) * 64 + c] = bfbits(W[(k * 64 + c) * 64 + o]);
    }
}

// ---------- pre-pass 2: per-(offset, 16-row tile) ranges ------------------
__global__ __launch_bounds__(256) void prep_rg(const int* __restrict__ imap,
                                               int P, int nt1,
                                               int* __restrict__ rg) {
    const int idx = blockIdx.x * 256 + threadIdx.x;
    if (idx >= NOFF * nt1) return;
    const int m = idx / nt1, t = idx % nt1;
    const int* a = imap + (size_t)m * P;
    const int target = t * TROWS;
    int lo = 0, hi = P;
    while (lo < hi) {
        const int mid = (lo + hi) >> 1;
        const int v = a[mid];
        const int key = (v < 0) ? 0x7fffffff : v;   // -1 tail pad -> +inf
        if (key < target) lo = mid + 1; else hi = mid;
    }
    rg[idx] = lo;
}

// ---------- W stage: ws (unswizzled [o][c] bf16) -> LDS swizzled ----------
// 16B-unit u within a 128B row: stored at u ^ (o&7). 256 threads x 32B.
__device__ inline void stage_w(const unsigned short* __restrict__ wt_k,
                               unsigned short* __restrict__ dst, int tid) {
    const int g0 = tid * 2;          // 16B-unit index, 0..511
    const int o  = g0 >> 3;
    const int q0 = g0 & 7;
    const ushort8 v0 = *(const ushort8*)(wt_k + g0 * 8);
    const ushort8 v1 = *(const ushort8*)(wt_k + g0 * 8 + 8);
    const int sw = o & 7;
    *(ushort8*)(dst + o * 64 + ((q0    ) ^ sw) * 8) = v0;
    *(ushort8*)(dst + o * 64 + ((q0 + 1) ^ sw) * 8) = v1;
}

// ---------- main ----------------------------------------------------------
__global__ __launch_bounds__(256) void spconv_v3(
    const float* __restrict__ feats,
    const unsigned short* __restrict__ wt,   // [27][64][64] bf16 (o-major)
    const int* __restrict__ imap, const int* __restrict__ omap,
    const int* __restrict__ rg,              // [26][nt+1]
    float* __restrict__ out, int N, int P, int nt)
{
    __shared__ unsigned short wbuf[2][4096]; // 2 x 8KB
    __shared__ int srctab[4][TROWS];

    const int tid = threadIdx.x, w = tid >> 6, lane = tid & 63;
    const int col = lane & 15, grp = lane >> 4;
    const int t = blockIdx.x * 4 + w;        // this wave's 16-row tile
    const bool vt = (t < nt);
    const int r0 = t * TROWS;
    const int nt1 = nt + 1;

    stage_w(wt + kk_of_item(0) * 4096, wbuf[0], tid);
    __syncthreads();

    f32x4 c0 = {0.f,0.f,0.f,0.f}, c1 = c0, c2 = c0, c3 = c0;

    for (int it = 0; it < 27; ++it) {
        const unsigned short* curb = wbuf[it & 1];
        if (it < 26)
            stage_w(wt + kk_of_item(it + 1) * 4096, wbuf[(it + 1) & 1], tid);

        // --- per-column source row for this item ---
        int src = -1;
        if (vt) {
            if (it < 26) {
                const int p0 = rg[it * nt1 + t];
                const int p1 = rg[it * nt1 + t + 1];
                const int cnt = p1 - p0;          // <= 16 guaranteed
                if (lane < TROWS) srctab[w][lane] = -1;
                if (lane < cnt) {
                    const int iv = imap[(size_t)it * P + p0 + lane] - r0;
                    const int ov = omap[(size_t)it * P + p0 + lane];
                    srctab[w][iv] = ov;           // in-order within wave
                }
                src = srctab[w][col];
            } else {
                src = (r0 + col < N) ? (r0 + col) : -1;   // center: identity
            }
        }

        // --- gather A rows (only real pairs), convert to bf16 ---
        bf16x8 a0 = {0,0,0,0,0,0,0,0}, a1 = a0;
        if (src >= 0) {
            const float4* fp = (const float4*)(feats + (size_t)src * 64 + grp * 8);
            const float4 x0 = fp[0], x1 = fp[1];
            const float4* fq = (const float4*)(feats + (size_t)src * 64 + 32 + grp * 8);
            const float4 y0 = fq[0], y1 = fq[1];
            a0[0]=(short)bfbits(x0.x); a0[1]=(short)bfbits(x0.y);
            a0[2]=(short)bfbits(x0.z); a0[3]=(short)bfbits(x0.w);
            a0[4]=(short)bfbits(x1.x); a0[5]=(short)bfbits(x1.y);
            a0[6]=(short)bfbits(x1.z); a0[7]=(short)bfbits(x1.w);
            a1[0]=(short)bfbits(y0.x); a1[1]=(short)bfbits(y0.y);
            a1[2]=(short)bfbits(y0.z); a1[3]=(short)bfbits(y0.w);
            a1[4]=(short)bfbits(y1.x); a1[5]=(short)bfbits(y1.y);
            a1[6]=(short)bfbits(y1.z); a1[7]=(short)bfbits(y1.w);
        }

        // --- MFMA: C[16 rows][64 couts] += A @ W[kk] ---
        if (vt) {
#pragma unroll
            for (int ot = 0; ot < 4; ++ot) {
                const int o = ot * 16 + col;
                const int sw = o & 7;
                const bf16x8 b0 = *(const bf16x8*)(curb + o * 64 + ((0 * 4 + grp) ^ sw) * 8);
                const bf16x8 b1 = *(const bf16x8*)(curb + o * 64 + ((1 * 4 + grp) ^ sw) * 8);
                f32x4& cc = (ot == 0) ? c0 : (ot == 1) ? c1 : (ot == 2) ? c2 : c3;
                cc = __builtin_amdgcn_mfma_f32_16x16x32_bf16(a0, b0, cc, 0, 0, 0);
                cc = __builtin_amdgcn_mfma_f32_16x16x32_bf16(a1, b1, cc, 0, 0, 0);
            }
        }
        __syncthreads();   // staged buffer ready; safe to overwrite other half
    }

    // --- single non-atomic write-out ---
    if (vt) {
#pragma unroll
        for (int ot = 0; ot < 4; ++ot) {
            const f32x4 cv = (ot == 0) ? c0 : (ot == 1) ? c1 : (ot == 2) ? c2 : c3;
#pragma unroll
            for (int reg = 0; reg < 4; ++reg) {
                const int r = r0 + grp * 4 + reg;
                if (r < N) out[(size_t)r * 64 + ot * 16 + col] = cv[reg];
            }
        }
    }
}

// ---------- fallback (round-0, fp32 + atomics) ----------------------------
template <int MODE>
__global__ __launch_bounds__(256) void spconv_fb(
    const float* __restrict__ feats, const float* __restrict__ W,
    const int* __restrict__ imap, const int* __restrict__ omap,
    float* __restrict__ out, int npairs)
{
    __shared__ float4 wt4[16 * 64];
    const int tid = threadIdx.x, koff = blockIdx.y;
    const float* Wk;
    const int* im = nullptr; const int* om = nullptr;
    if (MODE == 0) Wk = W + 13 * (CIN * COUT);
    else {
        const int kk = (koff < 13) ? koff : koff + 1;
        Wk = W + (size_t)kk * (CIN * COUT);
        im = imap + (size_t)koff * npairs; om = omap + (size_t)koff * npairs;
    }
    float* wts = (float*)wt4;
    for (int idx = tid; idx < CIN * COUT; idx += 256) {
        const int c = idx >> 6, o = idx & 63;
        wts[((c >> 2) * 64 + o) * 4 + (c & 3)] = Wk[idx];
    }
    __syncthreads();
    const int o = tid & 63, w = tid >> 6;
    const int base = blockIdx.x * 256 + w * 64;
    const float4* f4p = (const float4*)feats;
    for (int n = 0; n < 64; ++n) {
        const int p = base + n;
        if (p >= npairs) break;
        int i, j;
        if (MODE == 0) { i = p; j = p; }
        else { i = im[p]; if (i < 0) continue; j = om[p]; }
        i = __builtin_amdgcn_readfirstlane(i);
        float a = 0.f;
#pragma unroll
        for (int c4 = 0; c4 < 16; ++c4) {
            const float4 f = f4p[(size_t)i * 16 + c4];
            const float4 wv = wt4[c4 * 64 + o];
            a += f.x * wv.x + f.y * wv.y + f.z * wv.z + f.w * wv.w;
        }
        if (MODE == 0) out[(size_t)j * COUT + o] = a;
        else atomicAdd(&out[(size_t)j * COUT + o], a);
    }
}

extern "C" void kernel_launch(void* const* d_in, const int* in_sizes, int n_in,
                              void* d_out, int out_size, void* d_ws, size_t ws_size,
                              hipStream_t stream) {
    const float* feats = (const float*)d_in[0];
    const float* W     = (const float*)d_in[1];
    const int* imap    = (const int*)d_in[2];
    const int* omap    = (const int*)d_in[3];
    float* out         = (float*)d_out;

    const int N = in_sizes[0] / CIN;
    const int P = in_sizes[2] / NOFF;
    const int nt = (N + TROWS - 1) / TROWS;   // 16-row tiles (12500)
    const int nt1 = nt + 1;

    const size_t wt_bytes = 27 * 64 * 64 * sizeof(unsigned short);  // 221184
    const size_t rg_bytes = (size_t)NOFF * nt1 * sizeof(int);       // ~1.3 MB
    if (ws_size < wt_bytes + rg_bytes) {
        dim3 blk(256);
        dim3 gc((N + 255) / 256, 1);
        spconv_fb<0><<<gc, blk, 0, stream>>>(feats, W, nullptr, nullptr, out, N);
        dim3 go((P + 255) / 256, NOFF);
        spconv_fb<1><<<go, blk, 0, stream>>>(feats, W, imap, omap, out, P);
        return;
    }

    unsigned short* Wt = (unsigned short*)d_ws;
    int* rg = (int*)((char*)d_ws + wt_bytes);

    prep_wt<<<27, 256, 0, stream>>>(W, Wt);
    prep_rg<<<(NOFF * nt1 + 255) / 256, 256, 0, stream>>>(imap, P, nt1, rg);

    const int nblocks = (nt + 3) / 4;         // 4 waves (tiles) per block
    spconv_v3<<<nblocks, 256, 0, stream>>>(feats, Wt, imap, omap, rg, out, N, P, nt);
}